// Round 1
// baseline (593.460 us; speedup 1.0000x reference)
//
#include <hip/hip_runtime.h>

#define NDEPTH 8
#define NK 129          // union of all Cantor index sets (= depth-7 set)
#define SEQB 4096
#define DIM 512
#define ROWS 16         // q rows per block
#define NTHR 256
#define DC 64           // dims per LDS chunk
#define NCHUNK (DIM / DC)
#define SLOTS 9         // keys per thread: j = m + 16*s, s in [0,9)

// ---------------------------------------------------------------------------
// Compile-time replication of the reference's float64 Cantor-index pipeline.
// MUST be bit-exact with numpy float64: e.g. (1/3)*4095 truncates to 1364,
// not 1365. constexpr doubles use the same IEEE ops in the same order.
// ---------------------------------------------------------------------------
struct CTab {
    int uidx[NK];   // sorted union of key indices
    int minD[NK];   // first depth whose index set contains uidx[i]
    int count;
};

static constexpr CTab make_ctab() {
    CTab T{};
    double pos[NDEPTH][NK] = {};
    int cnt[NDEPTH] = {};
    pos[0][0] = 0.0; pos[0][1] = 1.0; cnt[0] = 2;
    for (int d = 1; d < NDEPTH; ++d) {
        const int n = cnt[d - 1];
        int m = 0;
        for (int i = 0; i < n - 1; ++i) {
            const double left  = pos[d - 1][i];
            const double right = pos[d - 1][i + 1];
            const double third = (right - left) / 3.0;
            pos[d][m++] = left;
            pos[d][m++] = left + third;
        }
        pos[d][m++] = pos[d - 1][n - 1];
        cnt[d] = m;
    }
    int idx[NDEPTH][NK] = {};
    int icnt[NDEPTH] = {};
    for (int d = 0; d < NDEPTH; ++d) {
        int m = 0;
        for (int i = 0; i < cnt[d]; ++i) {
            const long long v = (long long)(pos[d][i] * 4095.0);  // trunc == astype(int64)
            bool dup = false;
            for (int k = 0; k < m; ++k) if (idx[d][k] == (int)v) dup = true;
            if (!dup) idx[d][m++] = (int)v;
        }
        icnt[d] = m;
    }
    // union (depths are nested, but merge generically for safety)
    int u[2 * NK] = {};
    int un = 0;
    for (int d = 0; d < NDEPTH; ++d)
        for (int i = 0; i < icnt[d]; ++i) {
            const int v = idx[d][i];
            bool f = false;
            for (int k = 0; k < un; ++k) if (u[k] == v) f = true;
            if (!f && un < 2 * NK) u[un++] = v;
        }
    for (int i = 1; i < un; ++i) {          // insertion sort
        const int key = u[i];
        int k = i - 1;
        while (k >= 0 && u[k] > key) { u[k + 1] = u[k]; --k; }
        u[k + 1] = key;
    }
    T.count = un;
    for (int i = 0; i < un && i < NK; ++i) {
        T.uidx[i] = u[i];
        int md = NDEPTH;
        for (int d = 0; d < NDEPTH && md == NDEPTH; ++d)
            for (int k = 0; k < icnt[d]; ++k)
                if (idx[d][k] == u[i]) { md = d; break; }
        T.minD[i] = md;
    }
    return T;
}

static constexpr CTab h_ct = make_ctab();
static_assert(h_ct.count == NK, "cantor union size mismatch");
__device__ __constant__ CTab g_ct = h_ct;

// ---------------------------------------------------------------------------
// Fused kernel: scores -> bucketed multi-depth softmax -> PV, fp32.
// Block: 256 threads = (16 rows) x (16 lanes). Thread (r,m) owns keys m+16s.
// ---------------------------------------------------------------------------
__global__ __launch_bounds__(NTHR, 3) void ufa_kernel(
    const float* __restrict__ Q, const float* __restrict__ K,
    const float* __restrict__ V, const float* __restrict__ SW,
    const float* __restrict__ ST, float* __restrict__ Out)
{
    __shared__ float4 q_lds[ROWS][DC / 4 + 1];   // +1 float4 pad -> conflict-free
    __shared__ float4 k_lds[NK][DC / 4 + 1];
    __shared__ float  c_lds[ROWS][132];          // per-(row,key) coefficients

    const int t  = (int)threadIdx.x;
    const int r  = t >> 4;
    const int m  = t & 15;
    const int b  = (int)blockIdx.x >> 8;         // 256 q-tiles per batch
    const int q0 = ((int)blockIdx.x & 255) * ROWS;

    // depth weights: softmax(scale_weights / temperature), redundant per thread
    float w[NDEPTH];
    {
        const float it = 1.0f / ST[0];
        float mx = -3.0e38f;
        #pragma unroll
        for (int d = 0; d < NDEPTH; ++d) { w[d] = SW[d] * it; mx = fmaxf(mx, w[d]); }
        float sum = 0.0f;
        #pragma unroll
        for (int d = 0; d < NDEPTH; ++d) { w[d] = __expf(w[d] - mx); sum += w[d]; }
        const float is = 1.0f / sum;
        #pragma unroll
        for (int d = 0; d < NDEPTH; ++d) w[d] *= is;
    }

    // ---------------- Phase A: scores = Q . K_u^T (D-chunked LDS tiles) -----
    float acc[SLOTS];
    #pragma unroll
    for (int s = 0; s < SLOTS; ++s) acc[s] = 0.0f;

    const size_t qbase = ((size_t)b * SEQB + q0) * DIM;
    const size_t kbase = (size_t)b * SEQB * DIM;

    for (int c = 0; c < NCHUNK; ++c) {
        // stage Q chunk: one float4 per thread, coalesced
        q_lds[r][m] = *(const float4*)(Q + qbase + (size_t)r * DIM + c * DC + m * 4);
        // stage K union chunk: 16 rows per pass, 256B coalesced per row
        #pragma unroll
        for (int p = 0; p < 9; ++p) {
            const int row = p * 16 + r;
            if (row < NK) {
                k_lds[row][m] = *(const float4*)(K + kbase +
                    (size_t)g_ct.uidx[row] * DIM + c * DC + m * 4);
            }
        }
        __syncthreads();
        #pragma unroll 4
        for (int d4 = 0; d4 < DC / 4; ++d4) {
            const float4 q4 = q_lds[r][d4];          // broadcast across 16 lanes
            #pragma unroll
            for (int s = 0; s < 8; ++s) {
                const float4 k4 = k_lds[m + 16 * s][d4];
                acc[s] += q4.x * k4.x + q4.y * k4.y + q4.z * k4.z + q4.w * k4.w;
            }
            if (m == 0) {                            // key 128 tail (lane m==0)
                const float4 k4 = k_lds[128][d4];
                acc[8] += q4.x * k4.x + q4.y * k4.y + q4.z * k4.z + q4.w * k4.w;
            }
        }
        __syncthreads();
    }

    // ---------------- multi-depth softmax, collapsed via minDepth buckets ---
    const float inv_scale = 0.04419417382415922f;    // 1/sqrt(512)
    float sc[SLOTS];
    #pragma unroll
    for (int s = 0; s < SLOTS; ++s) {
        const int j = m + 16 * s;
        sc[s] = (j < NK) ? acc[s] * inv_scale : -3.0e38f;
    }
    float mx = sc[0];
    #pragma unroll
    for (int s = 1; s < SLOTS; ++s) mx = fmaxf(mx, sc[s]);
    #pragma unroll
    for (int off = 1; off < 16; off <<= 1) mx = fmaxf(mx, __shfl_xor(mx, off));

    float P[NDEPTH];
    #pragma unroll
    for (int d = 0; d < NDEPTH; ++d) P[d] = 0.0f;
    float e[SLOTS];
    #pragma unroll
    for (int s = 0; s < SLOTS; ++s) {
        const int j = m + 16 * s;
        if (j < NK) {
            e[s] = __expf(sc[s] - mx);
            const int md = g_ct.minD[j];
            #pragma unroll
            for (int d = 0; d < NDEPTH; ++d) P[d] += (md == d) ? e[s] : 0.0f;
        } else {
            e[s] = 0.0f;
        }
    }
    #pragma unroll
    for (int d = 0; d < NDEPTH; ++d) {
        #pragma unroll
        for (int off = 1; off < 16; off <<= 1) P[d] += __shfl_xor(P[d], off);
    }
    // L_d = prefix sums of buckets; T_md = suffix sum of w_d / L_d
    float T[NDEPTH];
    {
        float L = 0.0f, Lc[NDEPTH];
        #pragma unroll
        for (int d = 0; d < NDEPTH; ++d) { L += P[d]; Lc[d] = L; }
        float ta = 0.0f;
        #pragma unroll
        for (int d = NDEPTH - 1; d >= 0; --d) { ta += w[d] / Lc[d]; T[d] = ta; }
    }
    #pragma unroll
    for (int s = 0; s < SLOTS; ++s) {
        const int j = m + 16 * s;
        if (j < NK) {
            const int md = g_ct.minD[j];
            float tv = 0.0f;
            #pragma unroll
            for (int d = 0; d < NDEPTH; ++d) tv = (md == d) ? T[d] : tv;
            c_lds[r][j] = e[s] * tv;
        }
    }
    __syncthreads();

    // ---------------- Phase B: O = C . V_u (V from global, L2-resident) -----
    float4 o[8];
    #pragma unroll
    for (int s8 = 0; s8 < 8; ++s8) o[s8] = make_float4(0.f, 0.f, 0.f, 0.f);

    const float* Vb = V + kbase;
    #pragma unroll 2
    for (int j = 0; j < NK; ++j) {
        const float cj = c_lds[r][j];                       // 16-lane broadcast
        const float4* vrow = (const float4*)(Vb + (size_t)g_ct.uidx[j] * DIM) + m;
        #pragma unroll
        for (int s8 = 0; s8 < 8; ++s8) {
            const float4 v4 = vrow[s8 * 16];
            o[s8].x += cj * v4.x;
            o[s8].y += cj * v4.y;
            o[s8].z += cj * v4.z;
            o[s8].w += cj * v4.w;
        }
    }
    float4* orow = (float4*)(Out + qbase + (size_t)r * DIM) + m;
    #pragma unroll
    for (int s8 = 0; s8 < 8; ++s8) orow[s8 * 16] = o[s8];
}

// ---------------------------------------------------------------------------
extern "C" void kernel_launch(void* const* d_in, const int* in_sizes, int n_in,
                              void* d_out, int out_size, void* d_ws, size_t ws_size,
                              hipStream_t stream) {
    const float* Q  = (const float*)d_in[0];
    const float* K  = (const float*)d_in[1];
    const float* V  = (const float*)d_in[2];
    // d_in[3] = t, unused by the reference
    const float* SW = (const float*)d_in[4];
    const float* ST = (const float*)d_in[5];
    float* Out = (float*)d_out;

    const int B = in_sizes[0] / (SEQB * DIM);     // 8
    dim3 grid(B * (SEQB / ROWS));                 // 2048 blocks
    ufa_kernel<<<grid, NTHR, 0, stream>>>(Q, K, V, SW, ST, Out);
}

// Round 2
// 213.453 us; speedup vs baseline: 2.7803x; 2.7803x over previous
//
#include <hip/hip_runtime.h>

#define NDEPTH 8
#define NK 129
#define SEQB 4096
#define DIM 512

typedef short bf16x8 __attribute__((ext_vector_type(8)));   // 8 bf16 in 4 VGPRs
typedef float f32x4  __attribute__((ext_vector_type(4)));

// ---------------------------------------------------------------------------
// Compile-time replication of the reference float64 Cantor-index pipeline
// (bit-exact: (1/3)*4095 truncates to 1364, not 1365).
// ---------------------------------------------------------------------------
struct CTab { int uidx[NK]; int minD[NK]; int count; };

static constexpr CTab make_ctab() {
    CTab T{};
    double pos[NDEPTH][NK] = {}; int cnt[NDEPTH] = {};
    pos[0][0] = 0.0; pos[0][1] = 1.0; cnt[0] = 2;
    for (int d = 1; d < NDEPTH; ++d) {
        const int n = cnt[d - 1]; int m = 0;
        for (int i = 0; i < n - 1; ++i) {
            const double left = pos[d - 1][i], right = pos[d - 1][i + 1];
            const double third = (right - left) / 3.0;
            pos[d][m++] = left; pos[d][m++] = left + third;
        }
        pos[d][m++] = pos[d - 1][n - 1]; cnt[d] = m;
    }
    int idx[NDEPTH][NK] = {}; int icnt[NDEPTH] = {};
    for (int d = 0; d < NDEPTH; ++d) {
        int m = 0;
        for (int i = 0; i < cnt[d]; ++i) {
            const long long v = (long long)(pos[d][i] * 4095.0);
            bool dup = false;
            for (int k = 0; k < m; ++k) if (idx[d][k] == (int)v) dup = true;
            if (!dup) idx[d][m++] = (int)v;
        }
        icnt[d] = m;
    }
    int u[2 * NK] = {}; int un = 0;
    for (int d = 0; d < NDEPTH; ++d)
        for (int i = 0; i < icnt[d]; ++i) {
            const int v = idx[d][i]; bool f = false;
            for (int k = 0; k < un; ++k) if (u[k] == v) f = true;
            if (!f && un < 2 * NK) u[un++] = v;
        }
    for (int i = 1; i < un; ++i) {
        const int key = u[i]; int k = i - 1;
        while (k >= 0 && u[k] > key) { u[k + 1] = u[k]; --k; }
        u[k + 1] = key;
    }
    T.count = un;
    for (int i = 0; i < un && i < NK; ++i) {
        T.uidx[i] = u[i];
        int md = NDEPTH;
        for (int d = 0; d < NDEPTH && md == NDEPTH; ++d)
            for (int k = 0; k < icnt[d]; ++k)
                if (idx[d][k] == u[i]) { md = d; break; }
        T.minD[i] = md;
    }
    return T;
}
static constexpr CTab h_ct = make_ctab();
static_assert(h_ct.count == NK, "cantor union size mismatch");
__device__ __constant__ CTab g_ct = h_ct;

__device__ __forceinline__ short f2bf(float f) {       // RNE f32->bf16
    union { float f; unsigned u; } v; v.f = f;
    unsigned r = v.u + 0x7fffu + ((v.u >> 16) & 1u);
    return (short)(r >> 16);
}

__device__ __forceinline__ void gl_lds16(const void* g, void* lds) {
    __builtin_amdgcn_global_load_lds(
        (const __attribute__((address_space(1))) unsigned int*)g,
        (__attribute__((address_space(3))) unsigned int*)lds, 16, 0, 0);
}

// ws layout: wsK [8][144][512] bf16 (rows>=129 zero)  = 1,179,648 B
//            wsVt[8][512][192] bf16 (keys>=129 zero)  = 1,572,864 B
#define WSK_ELEMS (8 * 144 * 512)

// ---------------------------------------------------------------------------
// Prep: build bf16 K-union rows + transposed V-union (logical layout; swizzle
// is applied via source addresses in the main kernel's staging).
// ---------------------------------------------------------------------------
__global__ __launch_bounds__(256) void ufa_prep(
    const float* __restrict__ K, const float* __restrict__ V,
    short* __restrict__ ws)
{
    short* wsK  = ws;
    short* wsVt = ws + WSK_ELEMS;
    if (blockIdx.x < 1152) {                       // K rows: 8 batches x 144
        const int b = blockIdx.x / 144, key = blockIdx.x % 144;
        short* dst = wsK + ((size_t)b * 144 + key) * 512;
        if (key < NK) {
            const float* src = K + ((size_t)b * SEQB + g_ct.uidx[key]) * DIM;
            for (int i = threadIdx.x; i < 512; i += 256) dst[i] = f2bf(src[i]);
        } else {
            for (int i = threadIdx.x; i < 512; i += 256) dst[i] = 0;
        }
    } else {                                       // Vt tiles: 8 batches x 8
        __shared__ float tr[64][133];
        const int id = blockIdx.x - 1152;
        const int b = id / 8, dt = id % 8;
        const float* Vb = V + (size_t)b * SEQB * DIM;
        for (int it = 0; it < 33; ++it) {
            const int k = it * 4 + (int)threadIdx.x / 64;
            const int d = (int)threadIdx.x % 64;
            if (k < NK) tr[d][k] = Vb[(size_t)g_ct.uidx[k] * DIM + dt * 64 + d];
        }
        __syncthreads();
        short* dst = wsVt + ((size_t)b * 512 + dt * 64) * 192;
        for (int idx = threadIdx.x; idx < 64 * 192; idx += 256) {
            const int d = idx / 192, k = idx - d * 192;
            dst[(size_t)d * 192 + k] = (k < NK) ? f2bf(tr[d][k]) : (short)0;
        }
    }
}

// ---------------------------------------------------------------------------
// Main: Phase A  S = Q.K^T (MFMA, 9 key tiles) -> bucketed softmax ->
//       Phase B  O = C.Vt (MFMA). 512 blocks x 4 waves, 16 q-rows/wave.
// ---------------------------------------------------------------------------
__global__ __launch_bounds__(256, 2) void ufa_main(
    const float* __restrict__ Q, const short* __restrict__ ws,
    const float* __restrict__ SW, const float* __restrict__ ST,
    float* __restrict__ Out)
{
    __shared__ char smem[50176];
    char*  kv    = smem;                       // K tile [144][64] / Vt tile [64][192], XOR-swizzled
    short* c_lds = (short*)(smem + 24576);     // [4 waves][16 rows][200]

    const short* wsK  = ws;
    const short* wsVt = ws + WSK_ELEMS;

    const int t    = (int)threadIdx.x;
    const int w    = t >> 6;
    const int lane = t & 63;
    const int m    = lane & 15;
    const int quad = lane >> 4;
    const int b    = (int)blockIdx.x >> 6;
    const int q0   = ((int)blockIdx.x & 63) * 64 + w * 16;

    // depth-weight softmax (redundant per thread)
    float wgt[NDEPTH];
    {
        const float it = 1.0f / ST[0];
        float mx = -3.0e38f;
        #pragma unroll
        for (int d = 0; d < NDEPTH; ++d) { wgt[d] = SW[d] * it; mx = fmaxf(mx, wgt[d]); }
        float sum = 0.0f;
        #pragma unroll
        for (int d = 0; d < NDEPTH; ++d) { wgt[d] = __expf(wgt[d] - mx); sum += wgt[d]; }
        const float is = 1.0f / sum;
        #pragma unroll
        for (int d = 0; d < NDEPTH; ++d) wgt[d] *= is;
    }

    // ---------------- Phase A --------------------------------------------
    f32x4 acc[9];
    #pragma unroll
    for (int tt = 0; tt < 9; ++tt) acc[tt] = (f32x4){0.f, 0.f, 0.f, 0.f};

    const float* Qb  = Q + ((size_t)b * SEQB + q0 + m) * DIM;
    const short* wsKb = wsK + (size_t)b * 144 * 512;

    for (int c = 0; c < 8; ++c) {
        // stage K chunk [144][64] with XOR swizzle baked into source address
        for (int g = w; g < 18; g += 4) {
            const int off  = g * 1024 + lane * 16;
            const int row  = off >> 7;
            const int slot = (off >> 4) & 7;
            const int slog = slot ^ (row & 7);
            gl_lds16(wsKb + (size_t)row * 512 + c * 64 + slog * 8, kv + g * 1024);
        }
        // Q A-fragments from global (fp32 -> bf16 in-register)
        bf16x8 aq[2];
        #pragma unroll
        for (int ks = 0; ks < 2; ++ks) {
            const float* qp = Qb + c * 64 + ks * 32 + quad * 8;
            const float4 x = *(const float4*)qp;
            const float4 y = *(const float4*)(qp + 4);
            aq[ks][0] = f2bf(x.x); aq[ks][1] = f2bf(x.y);
            aq[ks][2] = f2bf(x.z); aq[ks][3] = f2bf(x.w);
            aq[ks][4] = f2bf(y.x); aq[ks][5] = f2bf(y.y);
            aq[ks][6] = f2bf(y.z); aq[ks][7] = f2bf(y.w);
        }
        __syncthreads();
        #pragma unroll
        for (int ks = 0; ks < 2; ++ks) {
            #pragma unroll
            for (int tt = 0; tt < 9; ++tt) {
                const int row  = tt * 16 + m;
                const int slog = (ks * 4 + quad) ^ (row & 7);
                const bf16x8 bk = *(const bf16x8*)(kv + row * 128 + slog * 16);
                acc[tt] = __builtin_amdgcn_mfma_f32_16x16x32_bf16(aq[ks], bk, acc[tt], 0, 0, 0);
            }
        }
        __syncthreads();
    }

    // ---------------- softmax in MFMA C-layout ----------------------------
    // lane holds rows quad*4+i (i=0..3), keys j=16*tt+m (tt=0..8)
    const float inv_scale = 0.04419417382415922f;
    int md9[9];
    #pragma unroll
    for (int tt = 0; tt < 9; ++tt) {
        const int j = tt * 16 + m;
        md9[tt] = (j < NK) ? g_ct.minD[j] : NDEPTH;      // NDEPTH = invalid
    }
    float ev[9][4], mxr[4];
    #pragma unroll
    for (int i = 0; i < 4; ++i) mxr[i] = -3.0e38f;
    #pragma unroll
    for (int tt = 0; tt < 9; ++tt) {
        const bool valid = (tt * 16 + m) < NK;
        #pragma unroll
        for (int i = 0; i < 4; ++i) {
            const float s = valid ? acc[tt][i] * inv_scale : -3.0e38f;
            ev[tt][i] = s;
            mxr[i] = fmaxf(mxr[i], s);
        }
    }
    #pragma unroll
    for (int off = 1; off < 16; off <<= 1)
        #pragma unroll
        for (int i = 0; i < 4; ++i) mxr[i] = fmaxf(mxr[i], __shfl_xor(mxr[i], off));

    float P[4][NDEPTH];
    #pragma unroll
    for (int i = 0; i < 4; ++i)
        #pragma unroll
        for (int d = 0; d < NDEPTH; ++d) P[i][d] = 0.0f;
    #pragma unroll
    for (int tt = 0; tt < 9; ++tt) {
        const int md = md9[tt];
        #pragma unroll
        for (int i = 0; i < 4; ++i) {
            const float e = __expf(ev[tt][i] - mxr[i]);   // masked -> exp(-huge)=0
            ev[tt][i] = e;
            #pragma unroll
            for (int d = 0; d < NDEPTH; ++d) P[i][d] += (md == d) ? e : 0.0f;
        }
    }
    #pragma unroll
    for (int off = 1; off < 16; off <<= 1)
        #pragma unroll
        for (int i = 0; i < 4; ++i)
            #pragma unroll
            for (int d = 0; d < NDEPTH; ++d) P[i][d] += __shfl_xor(P[i][d], off);

    float T[4][NDEPTH];
    #pragma unroll
    for (int i = 0; i < 4; ++i) {
        float L = 0.0f, Lc[NDEPTH];
        #pragma unroll
        for (int d = 0; d < NDEPTH; ++d) { L += P[i][d]; Lc[d] = L; }
        float ta = 0.0f;
        #pragma unroll
        for (int d = NDEPTH - 1; d >= 0; --d) { ta += wgt[d] / Lc[d]; T[i][d] = ta; }
    }
    // write bf16 coefficients to LDS: [wave][row 16][key 200], keys 129..159 zero
    #pragma unroll
    for (int tt = 0; tt < 10; ++tt) {
        const int j = tt * 16 + m;
        #pragma unroll
        for (int i = 0; i < 4; ++i) {
            float cv = 0.0f;
            if (tt < 9 && j < NK) {
                const int md = md9[tt];
                float tv = 0.0f;
                #pragma unroll
                for (int d = 0; d < NDEPTH; ++d) tv = (md == d) ? T[i][d] : tv;
                cv = ev[tt][i] * tv;
            }
            c_lds[(w * 16 + quad * 4 + i) * 200 + j] = f2bf(cv);
        }
    }
    __syncthreads();

    // ---------------- Phase B --------------------------------------------
    bf16x8 ac[5];
    #pragma unroll
    for (int ks = 0; ks < 5; ++ks)
        ac[ks] = *(const bf16x8*)&c_lds[(w * 16 + m) * 200 + ks * 32 + quad * 8];

    const short* wsVb = wsVt + (size_t)b * 512 * 192;
    float* Ob = Out + ((size_t)b * SEQB + q0) * DIM;

    for (int c2 = 0; c2 < 8; ++c2) {
        __syncthreads();                                   // kv reuse fence
        for (int g = w; g < 24; g += 4) {
            const int off  = g * 1024 + lane * 16;
            const int row  = off / 384;
            const int rem  = off - row * 384;
            const int slot = rem >> 4;
            const int slog = (slot & ~7) | ((slot & 7) ^ (row & 7));
            gl_lds16(wsVb + (size_t)(c2 * 64 + row) * 192 + slog * 8, kv + g * 1024);
        }
        __syncthreads();
        #pragma unroll
        for (int nt = 0; nt < 4; ++nt) {
            f32x4 o = (f32x4){0.f, 0.f, 0.f, 0.f};
            #pragma unroll
            for (int ks = 0; ks < 5; ++ks) {
                const int row  = nt * 16 + m;
                const int slot = ks * 4 + quad;
                const int slog = (slot & ~7) | ((slot & 7) ^ (row & 7));
                const bf16x8 bv = *(const bf16x8*)(kv + row * 384 + slog * 16);
                o = __builtin_amdgcn_mfma_f32_16x16x32_bf16(ac[ks], bv, o, 0, 0, 0);
            }
            const int n0 = c2 * 64 + nt * 16;
            #pragma unroll
            for (int i = 0; i < 4; ++i)
                Ob[(size_t)(quad * 4 + i) * DIM + n0 + m] = o[i];
        }
    }
}

// ---------------------------------------------------------------------------
extern "C" void kernel_launch(void* const* d_in, const int* in_sizes, int n_in,
                              void* d_out, int out_size, void* d_ws, size_t ws_size,
                              hipStream_t stream) {
    const float* Q  = (const float*)d_in[0];
    const float* K  = (const float*)d_in[1];
    const float* V  = (const float*)d_in[2];
    const float* SW = (const float*)d_in[4];
    const float* ST = (const float*)d_in[5];
    float* Out = (float*)d_out;
    short* ws  = (short*)d_ws;

    ufa_prep<<<dim3(1152 + 64), dim3(256), 0, stream>>>(K, V, ws);
    ufa_main<<<dim3(512), dim3(256), 0, stream>>>(Q, ws, SW, ST, Out);
}